// Round 8
// baseline (143.044 us; speedup 1.0000x reference)
//
#include <hip/hip_runtime.h>
#include <hip/hip_bf16.h>

#define BB 8
#define TT 2048
#define CC 1024
#define HH 64
#define NSPLIT 4

typedef __attribute__((ext_vector_type(8)))  short bf16x8;
typedef __attribute__((ext_vector_type(4)))  float f32x4;
typedef __attribute__((ext_vector_type(16))) float f32x16;
typedef __attribute__((ext_vector_type(8)))  unsigned short us8;
typedef __attribute__((ext_vector_type(4)))  unsigned short us4;
typedef unsigned int u32;

static __device__ __forceinline__ unsigned short f2bf(float f) {
    union { float f; unsigned int u; } v; v.f = f;
    unsigned int u = v.u;
    return (unsigned short)((u + 0x7FFFu + ((u >> 16) & 1u)) >> 16);  // RNE
}
static __device__ __forceinline__ float bf2f(unsigned short s) {
    union { u32 u; float f; } v; v.u = ((u32)s) << 16; return v.f;
}

// ---------------------------------------------------------------------------
// Kernel 0: W [C][H] fp32 -> Wt [3][H][C] bf16 (transposed), fold log2(e)/8
// into Wq so QK^T scores come out in the log2 domain. (unchanged)
// ---------------------------------------------------------------------------
__global__ __launch_bounds__(256) void prep_weights(
        const float* __restrict__ Wq, const float* __restrict__ Wk,
        const float* __restrict__ Wv, unsigned short* __restrict__ Wt) {
    __shared__ float tile[64][65];
    int w  = blockIdx.x >> 4;       // 0..2
    int c0 = (blockIdx.x & 15) * 64;
    const float* W = (w == 0) ? Wq : (w == 1) ? Wk : Wv;
    int li = threadIdx.x;
    {
        int c = li >> 2, h4 = (li & 3) * 16;
        const float* src = W + (size_t)(c0 + c) * HH + h4;
        #pragma unroll
        for (int i = 0; i < 4; ++i) {
            float4 v4 = *(const float4*)(src + i * 4);
            tile[c][h4 + i*4 + 0] = v4.x; tile[c][h4 + i*4 + 1] = v4.y;
            tile[c][h4 + i*4 + 2] = v4.z; tile[c][h4 + i*4 + 3] = v4.w;
        }
    }
    __syncthreads();
    float scale = (w == 0) ? 0.1803368802f : 1.0f;   // log2(e)/sqrt(64)
    int h = li >> 2, cg = (li & 3) * 16;
    unsigned short* dst = Wt + (size_t)w * HH * CC + (size_t)h * CC + c0 + cg;
    #pragma unroll
    for (int i = 0; i < 16; ++i) dst[i] = f2bf(tile[cg + i][h] * scale);
}

// ---------------------------------------------------------------------------
// Kernel 1: fused QKV projection — ROUND-8: reverted to the round-6 PASSED
// version (M=64, grid 256, counted vmcnt(2)). Round-7's M=32/grid-512
// regressed +1.8us: doubled W-restage fabric traffic and halved per-wave
// MFMA ILP outweighed the co-residency gain. Fabric bytes bind this kernel.
// ---------------------------------------------------------------------------
__global__ __launch_bounds__(512, 4) void proj_qkv(
        const float* __restrict__ x, const unsigned short* __restrict__ Wt,
        unsigned short* __restrict__ qws, unsigned short* __restrict__ kws,
        unsigned short* __restrict__ vws) {
    __shared__ unsigned short Xs[2][64 * 64];    // 8 KB each
    __shared__ unsigned short Ws[2][192 * 64];   // 24 KB each
    int tid = threadIdx.x;
    int wv = tid >> 6, lane = tid & 63;
    int quad = (lane >> 4) & 3, lq = lane & 15;
    int mg = wv >> 2, ng = wv & 3;
    int r0 = blockIdx.x * 64;

    int xr = tid >> 3, xg = tid & 7;
    const float* xsrc = x + (size_t)(r0 + xr) * CC + xg * 8;
    int xdst = xr * 64 + ((xg ^ (xr & 7)) * 8);
    float4 xa[2], xb[2];                         // 2-deep prefetch sets

    f32x4 acc[2][3];
    #pragma unroll
    for (int mt = 0; mt < 2; ++mt)
        #pragma unroll
        for (int nt = 0; nt < 3; ++nt)
            #pragma unroll
            for (int i = 0; i < 4; ++i) acc[mt][nt][i] = 0.0f;

    auto stageW = [&](int buf, int kc) {
        #pragma unroll
        for (int i = 0; i < 3; ++i) {
            int fp = tid + i * 512;            // 0..1535
            int r = fp >> 3, pb = fp & 7, g = pb ^ (r & 7);
            const u32 __attribute__((address_space(1)))* gsrc =
                (const u32 __attribute__((address_space(1)))*)
                    (Wt + (size_t)r * CC + kc * 64 + g * 8);
            u32 __attribute__((address_space(3)))* ldst =
                (u32 __attribute__((address_space(3)))*)(&Ws[buf][fp * 8]);
            __builtin_amdgcn_global_load_lds(gsrc, ldst, 16, 0, 0);
        }
    };
    auto loadX = [&](int set, int kc) {
        xa[set] = *(const float4*)(xsrc + kc * 64);
        xb[set] = *(const float4*)(xsrc + kc * 64 + 4);
    };
    auto writeX = [&](int set, int buf) {
        unsigned short h[8];
        h[0]=f2bf(xa[set].x); h[1]=f2bf(xa[set].y);
        h[2]=f2bf(xa[set].z); h[3]=f2bf(xa[set].w);
        h[4]=f2bf(xb[set].x); h[5]=f2bf(xb[set].y);
        h[6]=f2bf(xb[set].z); h[7]=f2bf(xb[set].w);
        *(us8*)&Xs[buf][xdst] = *(const us8*)h;
    };

    stageW(0, 0);
    loadX(0, 0); loadX(1, 1);
    writeX(0, 0);

    for (int kc = 0; kc < 16; ++kc) {
        int cur = kc & 1;
        if (kc < 15) asm volatile("s_waitcnt vmcnt(2) lgkmcnt(0)" ::: "memory");
        else         asm volatile("s_waitcnt vmcnt(0) lgkmcnt(0)" ::: "memory");
        __builtin_amdgcn_sched_barrier(0);
        __builtin_amdgcn_s_barrier();        // all waves' buf[cur] now valid
        if (kc < 15) stageW(1 - cur, kc + 1);
        if (kc < 14) loadX(kc & 1, kc + 2);
        #pragma unroll
        for (int ks = 0; ks < 2; ++ks) {
            int g = ks * 4 + quad;
            bf16x8 a[2], b[3];
            #pragma unroll
            for (int mt = 0; mt < 2; ++mt) {
                int arow = mg * 32 + mt * 16 + lq;
                a[mt] = *(const bf16x8*)&Xs[cur][arow * 64 + (g ^ (lq & 7)) * 8];
            }
            #pragma unroll
            for (int nt = 0; nt < 3; ++nt) {
                int brow = ng * 48 + nt * 16 + lq;
                b[nt] = *(const bf16x8*)&Ws[cur][brow * 64 + (g ^ (lq & 7)) * 8];
            }
            #pragma unroll
            for (int mt = 0; mt < 2; ++mt)
                #pragma unroll
                for (int nt = 0; nt < 3; ++nt)
                    acc[mt][nt] = __builtin_amdgcn_mfma_f32_16x16x32_bf16(
                        a[mt], b[nt], acc[mt][nt], 0, 0, 0);
        }
        if (kc < 15) writeX((kc + 1) & 1, 1 - cur);  // X[kc+1]
    }

    // epilogue: direct q|k|v writes (wave-uniform column buckets).
    int bidx = r0 >> 11;                       // batch
    int t0base = r0 & (TT - 1);
    #pragma unroll
    for (int mt = 0; mt < 2; ++mt) {
        #pragma unroll
        for (int nt = 0; nt < 3; ++nt) {
            int gcol = ng * 48 + nt * 16 + lq;
            int rloc = mg * 32 + mt * 16 + quad * 4;      // + i
            if (gcol < 64) {
                #pragma unroll
                for (int i = 0; i < 4; ++i)
                    qws[(size_t)(r0 + rloc + i) * HH + gcol] =
                        f2bf(acc[mt][nt][i]);
            } else if (gcol < 128) {
                #pragma unroll
                for (int i = 0; i < 4; ++i)
                    kws[(size_t)(r0 + rloc + i) * HH + (gcol - 64)] =
                        f2bf(acc[mt][nt][i]);
            } else {
                unsigned short o[4];
                #pragma unroll
                for (int i = 0; i < 4; ++i) o[i] = f2bf(acc[mt][nt][i]);
                *(us4*)(vws + ((size_t)bidx * HH + (gcol - 128)) * TT
                            + t0base + rloc) = *(const us4*)o;
            }
        }
    }
}

// ---------------------------------------------------------------------------
// Kernel 2: causal attention — ROUND-8 CHANGE: double-buffered K/V LDS ->
// ONE barrier per chunk-iter (was 2). Compute reads buf[cur] while the
// T14-prefetched regs write buf[1-cur]; the single barrier both publishes
// the writes and retires the reads (disjoint buffers, no intra-iter race).
// LDS 45KB -> still 2-3 blocks/CU of 160KB. 64-key chunks, NSPLIT=4,
// setprio kept (round-6 structure otherwise).
// ---------------------------------------------------------------------------
__global__ __launch_bounds__(128, 2) void attn(
        const unsigned short* __restrict__ qws,
        const unsigned short* __restrict__ kws,
        const unsigned short* __restrict__ vws,
        unsigned short* __restrict__ Op, float* __restrict__ Lp) {
    __shared__ unsigned short Kt[2][64][72];   // [buf][key][h]
    __shared__ unsigned short Vt[2][64][72];   // [buf][h][key]
    __shared__ unsigned short Ps[64][72];      // [q][key], rows wave-private
    int ti = blockIdx.x;            // 64-row q tile, 0..31
    int s  = blockIdx.y;            // kv split 0..NSPLIT-1
    int b  = blockIdx.z;
    if (s > ti) return;             // chunk indices for this tile: 0..ti
    int tid = threadIdx.x, wv = tid >> 6, lane = tid & 63;
    int half = lane >> 5, l31 = lane & 31;

    bf16x8 qf[4];
    {
        const unsigned short* qp =
            qws + ((size_t)b * TT + ti * 64 + wv * 32 + l31) * HH + half * 8;
        #pragma unroll
        for (int ks = 0; ks < 4; ++ks) qf[ks] = *(const bf16x8*)(qp + ks * 16);
    }
    f32x16 O0, O1, Lc;
    #pragma unroll
    for (int i = 0; i < 16; ++i) { O0[i] = 0.f; O1[i] = 0.f; Lc[i] = 0.f; }
    bf16x8 ones;
    #pragma unroll
    for (int i = 0; i < 8; ++i) ones[i] = (short)0x3F80;

    int sr = tid >> 3, sg = tid & 7;
    const unsigned short* ksrc0 = kws + ((size_t)b * TT + sr) * HH + sg * 8;
    const unsigned short* vsrc0 = vws + ((size_t)b * HH + sr) * TT + sg * 8;

    us8 rk[4], rv[4];                          // T14 prefetch registers
    auto loadKV = [&](int jc) {
        #pragma unroll
        for (int i = 0; i < 4; ++i)
            rk[i] = *(const us8*)(ksrc0 + (size_t)(jc * 64 + i * 16) * HH);
        #pragma unroll
        for (int i = 0; i < 4; ++i)
            rv[i] = *(const us8*)(vsrc0 + (size_t)(i * 16) * TT + jc * 64);
    };
    auto writeKV = [&](int buf) {
        #pragma unroll
        for (int i = 0; i < 4; ++i) *(us8*)&Kt[buf][sr + i * 16][sg * 8] = rk[i];
        #pragma unroll
        for (int i = 0; i < 4; ++i) *(us8*)&Vt[buf][sr + i * 16][sg * 8] = rv[i];
    };

    // prologue: chunk s -> buf0
    loadKV(s);
    writeKV(0);
    int cur = 0;
    for (int jc = s; jc <= ti; jc += NSPLIT) {
        __syncthreads();   // publishes buf[cur] writes; retires prior reads
        bool more = (jc + NSPLIT <= ti);
        if (more) loadKV(jc + NSPLIT);         // global->regs, hides under MFMA
        f32x16 S0, S1;
        #pragma unroll
        for (int i = 0; i < 16; ++i) { S0[i] = 0.f; S1[i] = 0.f; }
        __builtin_amdgcn_s_setprio(1);
        #pragma unroll
        for (int ks = 0; ks < 4; ++ks) {
            bf16x8 kf0 = *(const bf16x8*)&Kt[cur][l31][ks * 16 + half * 8];
            bf16x8 kf1 = *(const bf16x8*)&Kt[cur][32 + l31][ks * 16 + half * 8];
            S0 = __builtin_amdgcn_mfma_f32_32x32x16_bf16(qf[ks], kf0, S0, 0, 0, 0);
            S1 = __builtin_amdgcn_mfma_f32_32x32x16_bf16(qf[ks], kf1, S1, 0, 0, 0);
        }
        __builtin_amdgcn_s_setprio(0);
        bool diag = (jc == ti);    // only the diagonal chunk needs masking
        #pragma unroll
        for (int r = 0; r < 16; ++r) {
            int pat = (r & 3) + 8 * (r >> 2) + 4 * half;    // local q row in wave
            float p0 = __builtin_amdgcn_exp2f(S0[r]);
            float p1 = __builtin_amdgcn_exp2f(S1[r]);
            if (diag) {
                int rloc = wv * 32 + pat;      // q row within the 64-tile
                if (l31 > rloc)      p0 = 0.0f;
                if (32 + l31 > rloc) p1 = 0.0f;
            }
            Ps[wv * 32 + pat][l31]      = f2bf(p0);
            Ps[wv * 32 + pat][32 + l31] = f2bf(p1);
        }
        // no __syncthreads: each wave reads only its own 32 Ps rows
        __builtin_amdgcn_s_setprio(1);
        #pragma unroll
        for (int ks = 0; ks < 4; ++ks) {
            bf16x8 pa  = *(const bf16x8*)&Ps[wv * 32 + l31][ks * 16 + half * 8];
            bf16x8 vf0 = *(const bf16x8*)&Vt[cur][l31][ks * 16 + half * 8];
            bf16x8 vf1 = *(const bf16x8*)&Vt[cur][32 + l31][ks * 16 + half * 8];
            O0 = __builtin_amdgcn_mfma_f32_32x32x16_bf16(pa, vf0, O0, 0, 0, 0);
            O1 = __builtin_amdgcn_mfma_f32_32x32x16_bf16(pa, vf1, O1, 0, 0, 0);
            Lc = __builtin_amdgcn_mfma_f32_32x32x16_bf16(pa, ones, Lc, 0, 0, 0);
        }
        __builtin_amdgcn_s_setprio(0);
        if (more) writeKV(1 - cur);            // regs -> other buffer
        cur ^= 1;
    }
    // deterministic per-split partial store (bf16)
    unsigned short* Ob =
        Op + (((size_t)s * BB + b) * TT + ti * 64 + wv * 32) * HH;
    #pragma unroll
    for (int r = 0; r < 16; ++r) {
        int pat = (r & 3) + 8 * (r >> 2) + 4 * half;
        Ob[(size_t)pat * HH + l31]      = f2bf(O0[r]);
        Ob[(size_t)pat * HH + 32 + l31] = f2bf(O1[r]);
    }
    if (l31 == 0) {
        #pragma unroll
        for (int r = 0; r < 16; ++r) {
            int pat = (r & 3) + 8 * (r >> 2) + 4 * half;
            Lp[((size_t)s * BB + b) * TT + ti * 64 + wv * 32 + pat] = Lc[r];
        }
    }
}

// ---------------------------------------------------------------------------
// Kernel 3: out = (sum_s Op[s]) / (sum_s Lp[s]) — unchanged (round-6).
// ---------------------------------------------------------------------------
__global__ __launch_bounds__(256) void norm_out(
        const unsigned short* __restrict__ Op, const float* __restrict__ Lp,
        float* __restrict__ out) {
    int idx = blockIdx.x * 256 + threadIdx.x;     // 65536 total
    int g = idx >> 2;                             // global row b*T + t, <16384
    int hseg = (idx & 3) * 16;
    int ti = (g & (TT - 1)) >> 6;
    int ns = min(ti + 1, NSPLIT);
    float a[16];
    #pragma unroll
    for (int j = 0; j < 16; ++j) a[j] = 0.f;
    float Ls = 0.f;
    for (int s = 0; s < ns; ++s) {
        const unsigned short* base =
            Op + ((size_t)s * BB * TT + g) * HH + hseg;
        us8 u0 = *(const us8*)base;
        us8 u1 = *(const us8*)(base + 8);
        #pragma unroll
        for (int j = 0; j < 8; ++j) { a[j] += bf2f(u0[j]); a[8 + j] += bf2f(u1[j]); }
        Ls += Lp[(size_t)s * BB * TT + g];
    }
    float inv = 1.0f / Ls;
    float* ob = out + (size_t)g * HH + hseg;
    #pragma unroll
    for (int q = 0; q < 4; ++q) {
        float4 v = make_float4(a[q*4] * inv, a[q*4+1] * inv,
                               a[q*4+2] * inv, a[q*4+3] * inv);
        ((float4*)ob)[q] = v;
    }
}

// ---------------------------------------------------------------------------
extern "C" void kernel_launch(void* const* d_in, const int* in_sizes, int n_in,
                              void* d_out, int out_size, void* d_ws, size_t ws_size,
                              hipStream_t stream) {
    (void)in_sizes; (void)n_in; (void)out_size; (void)ws_size;
    const float* x  = (const float*)d_in[0];
    const float* Wq = (const float*)d_in[1];
    const float* Wk = (const float*)d_in[2];
    const float* Wv = (const float*)d_in[3];
    float* out = (float*)d_out;

    char* ws = (char*)d_ws;
    unsigned short* Wt  = (unsigned short*)ws;                          // 384 KB
    unsigned short* qws = (unsigned short*)(ws + (1u << 19));           // 2 MB
    unsigned short* kws = (unsigned short*)(ws + (1u << 19) + (1u << 21));
    unsigned short* vws = (unsigned short*)(ws + (1u << 19) + (2u << 21));
    unsigned short* Op  = (unsigned short*)(ws + (1u << 19) + (3u << 21)); // 8 MB bf16 (4 splits)
    float*          Lp  = (float*)(ws + (1u << 19) + (3u << 21) + (1u << 24)); // 256 KB

    prep_weights<<<48, 256, 0, stream>>>(Wq, Wk, Wv, Wt);
    proj_qkv<<<256, 512, 0, stream>>>(x, Wt, qws, kws, vws);
    attn<<<dim3(32, NSPLIT, 8), 128, 0, stream>>>(qws, kws, vws, Op, Lp);
    norm_out<<<256, 256, 0, stream>>>(Op, Lp, out);
}

// Round 9
// 134.282 us; speedup vs baseline: 1.0653x; 1.0653x over previous
//
#include <hip/hip_runtime.h>
#include <hip/hip_bf16.h>

#define BB 8
#define TT 2048
#define CC 1024
#define HH 64
#define NSPLIT 4

typedef __attribute__((ext_vector_type(8)))  short bf16x8;
typedef __attribute__((ext_vector_type(4)))  float f32x4;
typedef __attribute__((ext_vector_type(16))) float f32x16;
typedef __attribute__((ext_vector_type(8)))  unsigned short us8;
typedef __attribute__((ext_vector_type(4)))  unsigned short us4;
typedef unsigned int u32;

static __device__ __forceinline__ unsigned short f2bf(float f) {
    union { float f; unsigned int u; } v; v.f = f;
    unsigned int u = v.u;
    return (unsigned short)((u + 0x7FFFu + ((u >> 16) & 1u)) >> 16);  // RNE
}
static __device__ __forceinline__ float bf2f(unsigned short s) {
    union { u32 u; float f; } v; v.u = ((u32)s) << 16; return v.f;
}

// ---------------------------------------------------------------------------
// Kernel 0: W [C][H] fp32 -> Wt [3][H][C] bf16 (transposed), fold log2(e)/8
// into Wq so QK^T scores come out in the log2 domain. (unchanged)
// ---------------------------------------------------------------------------
__global__ __launch_bounds__(256) void prep_weights(
        const float* __restrict__ Wq, const float* __restrict__ Wk,
        const float* __restrict__ Wv, unsigned short* __restrict__ Wt) {
    __shared__ float tile[64][65];
    int w  = blockIdx.x >> 4;       // 0..2
    int c0 = (blockIdx.x & 15) * 64;
    const float* W = (w == 0) ? Wq : (w == 1) ? Wk : Wv;
    int li = threadIdx.x;
    {
        int c = li >> 2, h4 = (li & 3) * 16;
        const float* src = W + (size_t)(c0 + c) * HH + h4;
        #pragma unroll
        for (int i = 0; i < 4; ++i) {
            float4 v4 = *(const float4*)(src + i * 4);
            tile[c][h4 + i*4 + 0] = v4.x; tile[c][h4 + i*4 + 1] = v4.y;
            tile[c][h4 + i*4 + 2] = v4.z; tile[c][h4 + i*4 + 3] = v4.w;
        }
    }
    __syncthreads();
    float scale = (w == 0) ? 0.1803368802f : 1.0f;   // log2(e)/sqrt(64)
    int h = li >> 2, cg = (li & 3) * 16;
    unsigned short* dst = Wt + (size_t)w * HH * CC + (size_t)h * CC + c0 + cg;
    #pragma unroll
    for (int i = 0; i < 16; ++i) dst[i] = f2bf(tile[cg + i][h] * scale);
}

// ---------------------------------------------------------------------------
// Kernel 1: fused QKV projection — ROUND-9 CHANGE: deeper prefetch pipeline.
// W triple-buffered in LDS (stageW(kc+2) -> ~2 compute phases of L2-latency
// cover) and X triple register set (loadX(kc+3) -> ~3 phases vs ~900cy cold
// HBM). K-loop fully unrolled so all buffer indices are compile-time (no
// dynamic reg-array indexing -> no scratch); sched_barrier(0) pins VMEM
// issue order so counted waits are exact: vmcnt(7) steady (drain W(kc),
// keep W(kc+1)x3+X(kc+2)x2+X(kc+3)x2 minus the writeX-drained set), tail
// vmcnt(5)/vmcnt(0). LDS 88KB (grid 256 = 1 block/CU, no occupancy cost).
// K-summation order per output element unchanged -> identical results.
// ---------------------------------------------------------------------------
__global__ __launch_bounds__(512, 4) void proj_qkv(
        const float* __restrict__ x, const unsigned short* __restrict__ Wt,
        unsigned short* __restrict__ qws, unsigned short* __restrict__ kws,
        unsigned short* __restrict__ vws) {
    __shared__ unsigned short Xs[2][64 * 64];    // 8 KB each (double)
    __shared__ unsigned short Ws[3][192 * 64];   // 24 KB each (triple)
    int tid = threadIdx.x;
    int wv = tid >> 6, lane = tid & 63;
    int quad = (lane >> 4) & 3, lq = lane & 15;
    int mg = wv >> 2, ng = wv & 3;
    int r0 = blockIdx.x * 64;

    int xr = tid >> 3, xg = tid & 7;
    const float* xsrc = x + (size_t)(r0 + xr) * CC + xg * 8;
    int xdst = xr * 64 + ((xg ^ (xr & 7)) * 8);
    float4 xa[3], xb[3];                         // 3-deep prefetch sets

    f32x4 acc[2][3];
    #pragma unroll
    for (int mt = 0; mt < 2; ++mt)
        #pragma unroll
        for (int nt = 0; nt < 3; ++nt)
            #pragma unroll
            for (int i = 0; i < 4; ++i) acc[mt][nt][i] = 0.0f;

    auto stageW = [&](int kc) {                  // chunk kc -> Ws[kc%3]
        int buf = kc % 3;
        #pragma unroll
        for (int i = 0; i < 3; ++i) {
            int fp = tid + i * 512;            // 0..1535
            int r = fp >> 3, pb = fp & 7, g = pb ^ (r & 7);
            const u32 __attribute__((address_space(1)))* gsrc =
                (const u32 __attribute__((address_space(1)))*)
                    (Wt + (size_t)r * CC + kc * 64 + g * 8);
            u32 __attribute__((address_space(3)))* ldst =
                (u32 __attribute__((address_space(3)))*)(&Ws[buf][fp * 8]);
            __builtin_amdgcn_global_load_lds(gsrc, ldst, 16, 0, 0);
        }
    };
    auto loadX = [&](int kc) {                   // chunk kc -> set kc%3
        int set = kc % 3;
        xa[set] = *(const float4*)(xsrc + kc * 64);
        xb[set] = *(const float4*)(xsrc + kc * 64 + 4);
    };
    auto writeX = [&](int kc) {                  // set kc%3 -> Xs[kc&1]
        int set = kc % 3;
        unsigned short h[8];
        h[0]=f2bf(xa[set].x); h[1]=f2bf(xa[set].y);
        h[2]=f2bf(xa[set].z); h[3]=f2bf(xa[set].w);
        h[4]=f2bf(xb[set].x); h[5]=f2bf(xb[set].y);
        h[6]=f2bf(xb[set].z); h[7]=f2bf(xb[set].w);
        *(us8*)&Xs[kc & 1][xdst] = *(const us8*)h;
    };

    // prologue: X(0) first (oldest, so writeX(0) drains ONLY it), then W(0),
    // W(1), X(1), X(2) stay in flight across the prologue.
    loadX(0);
    __builtin_amdgcn_sched_barrier(0);
    stageW(0); stageW(1);
    __builtin_amdgcn_sched_barrier(0);
    loadX(1); loadX(2);
    __builtin_amdgcn_sched_barrier(0);
    writeX(0);

    #pragma unroll
    for (int kc = 0; kc < 16; ++kc) {
        // counted wait: drain stageW(kc); keep deeper prefetches in flight
        if (kc <= 13)      asm volatile("s_waitcnt vmcnt(7) lgkmcnt(0)" ::: "memory");
        else if (kc == 14) asm volatile("s_waitcnt vmcnt(5) lgkmcnt(0)" ::: "memory");
        else               asm volatile("s_waitcnt vmcnt(0) lgkmcnt(0)" ::: "memory");
        __builtin_amdgcn_sched_barrier(0);
        __builtin_amdgcn_s_barrier();        // all waves' Ws[kc%3]/Xs[kc&1] valid
        if (kc <= 13) stageW(kc + 2);
        __builtin_amdgcn_sched_barrier(0);   // pin VMEM order: W before X
        if (kc <= 12) loadX(kc + 3);
        __builtin_amdgcn_sched_barrier(0);
        #pragma unroll
        for (int ks = 0; ks < 2; ++ks) {
            int g = ks * 4 + quad;
            bf16x8 a[2], b[3];
            #pragma unroll
            for (int mt = 0; mt < 2; ++mt) {
                int arow = mg * 32 + mt * 16 + lq;
                a[mt] = *(const bf16x8*)&Xs[kc & 1][arow * 64 + (g ^ (lq & 7)) * 8];
            }
            #pragma unroll
            for (int nt = 0; nt < 3; ++nt) {
                int brow = ng * 48 + nt * 16 + lq;
                b[nt] = *(const bf16x8*)&Ws[kc % 3][brow * 64 + (g ^ (lq & 7)) * 8];
            }
            #pragma unroll
            for (int mt = 0; mt < 2; ++mt)
                #pragma unroll
                for (int nt = 0; nt < 3; ++nt)
                    acc[mt][nt] = __builtin_amdgcn_mfma_f32_16x16x32_bf16(
                        a[mt], b[nt], acc[mt][nt], 0, 0, 0);
        }
        if (kc <= 14) writeX(kc + 1);        // implicit vmcnt drains X(kc+1) only
    }

    // epilogue: direct q|k|v writes (wave-uniform column buckets).
    int bidx = r0 >> 11;                       // batch
    int t0base = r0 & (TT - 1);
    #pragma unroll
    for (int mt = 0; mt < 2; ++mt) {
        #pragma unroll
        for (int nt = 0; nt < 3; ++nt) {
            int gcol = ng * 48 + nt * 16 + lq;
            int rloc = mg * 32 + mt * 16 + quad * 4;      // + i
            if (gcol < 64) {
                #pragma unroll
                for (int i = 0; i < 4; ++i)
                    qws[(size_t)(r0 + rloc + i) * HH + gcol] =
                        f2bf(acc[mt][nt][i]);
            } else if (gcol < 128) {
                #pragma unroll
                for (int i = 0; i < 4; ++i)
                    kws[(size_t)(r0 + rloc + i) * HH + (gcol - 64)] =
                        f2bf(acc[mt][nt][i]);
            } else {
                unsigned short o[4];
                #pragma unroll
                for (int i = 0; i < 4; ++i) o[i] = f2bf(acc[mt][nt][i]);
                *(us4*)(vws + ((size_t)bidx * HH + (gcol - 128)) * TT
                            + t0base + rloc) = *(const us4*)o;
            }
        }
    }
}

// ---------------------------------------------------------------------------
// Kernel 2: causal attention — ROUND-9: reverted to round-6 PASSED version
// verbatim (64-key chunks, NSPLIT=4, two barriers, single-buffer 27.6KB LDS,
// T14 reg-prefetch, T5 setprio). Round-8's single-barrier dbuf regressed
// +11.6us: 45KB LDS cut co-residency 5->3 blocks/CU and the merged barrier
// serialized waves on the slowest writer. Occupancy > barrier count here.
// ---------------------------------------------------------------------------
__global__ __launch_bounds__(128, 2) void attn(
        const unsigned short* __restrict__ qws,
        const unsigned short* __restrict__ kws,
        const unsigned short* __restrict__ vws,
        unsigned short* __restrict__ Op, float* __restrict__ Lp) {
    __shared__ unsigned short Kt[64][72];   // [key][h]
    __shared__ unsigned short Vt[64][72];   // [h][key]
    __shared__ unsigned short Ps[64][72];   // [q][key], rows wave-private
    int ti = blockIdx.x;            // 64-row q tile, 0..31
    int s  = blockIdx.y;            // kv split 0..NSPLIT-1
    int b  = blockIdx.z;
    if (s > ti) return;             // chunk indices for this tile: 0..ti
    int tid = threadIdx.x, wv = tid >> 6, lane = tid & 63;
    int half = lane >> 5, l31 = lane & 31;

    bf16x8 qf[4];
    {
        const unsigned short* qp =
            qws + ((size_t)b * TT + ti * 64 + wv * 32 + l31) * HH + half * 8;
        #pragma unroll
        for (int ks = 0; ks < 4; ++ks) qf[ks] = *(const bf16x8*)(qp + ks * 16);
    }
    f32x16 O0, O1, Lc;
    #pragma unroll
    for (int i = 0; i < 16; ++i) { O0[i] = 0.f; O1[i] = 0.f; Lc[i] = 0.f; }
    bf16x8 ones;
    #pragma unroll
    for (int i = 0; i < 8; ++i) ones[i] = (short)0x3F80;

    int sr = tid >> 3, sg = tid & 7;
    const unsigned short* ksrc0 = kws + ((size_t)b * TT + sr) * HH + sg * 8;
    const unsigned short* vsrc0 = vws + ((size_t)b * HH + sr) * TT + sg * 8;

    us8 rk[4], rv[4];                          // T14 prefetch registers
    auto loadKV = [&](int jc) {
        #pragma unroll
        for (int i = 0; i < 4; ++i)
            rk[i] = *(const us8*)(ksrc0 + (size_t)(jc * 64 + i * 16) * HH);
        #pragma unroll
        for (int i = 0; i < 4; ++i)
            rv[i] = *(const us8*)(vsrc0 + (size_t)(i * 16) * TT + jc * 64);
    };
    auto writeKV = [&]() {
        #pragma unroll
        for (int i = 0; i < 4; ++i) *(us8*)&Kt[sr + i * 16][sg * 8] = rk[i];
        #pragma unroll
        for (int i = 0; i < 4; ++i) *(us8*)&Vt[sr + i * 16][sg * 8] = rv[i];
    };

    loadKV(s);                                 // prologue prefetch
    for (int jc = s; jc <= ti; jc += NSPLIT) {
        __syncthreads();   // prior iter's K/V reads done before restage
        writeKV();
        if (jc + NSPLIT <= ti) loadKV(jc + NSPLIT);   // hide under compute
        __syncthreads();
        f32x16 S0, S1;
        #pragma unroll
        for (int i = 0; i < 16; ++i) { S0[i] = 0.f; S1[i] = 0.f; }
        __builtin_amdgcn_s_setprio(1);
        #pragma unroll
        for (int ks = 0; ks < 4; ++ks) {
            bf16x8 kf0 = *(const bf16x8*)&Kt[l31][ks * 16 + half * 8];
            bf16x8 kf1 = *(const bf16x8*)&Kt[32 + l31][ks * 16 + half * 8];
            S0 = __builtin_amdgcn_mfma_f32_32x32x16_bf16(qf[ks], kf0, S0, 0, 0, 0);
            S1 = __builtin_amdgcn_mfma_f32_32x32x16_bf16(qf[ks], kf1, S1, 0, 0, 0);
        }
        __builtin_amdgcn_s_setprio(0);
        bool diag = (jc == ti);    // only the diagonal chunk needs masking
        #pragma unroll
        for (int r = 0; r < 16; ++r) {
            int pat = (r & 3) + 8 * (r >> 2) + 4 * half;    // local q row in wave
            float p0 = __builtin_amdgcn_exp2f(S0[r]);
            float p1 = __builtin_amdgcn_exp2f(S1[r]);
            if (diag) {
                int rloc = wv * 32 + pat;      // q row within the 64-tile
                if (l31 > rloc)      p0 = 0.0f;
                if (32 + l31 > rloc) p1 = 0.0f;
            }
            Ps[wv * 32 + pat][l31]      = f2bf(p0);
            Ps[wv * 32 + pat][32 + l31] = f2bf(p1);
        }
        // no __syncthreads: each wave reads only its own 32 Ps rows
        __builtin_amdgcn_s_setprio(1);
        #pragma unroll
        for (int ks = 0; ks < 4; ++ks) {
            bf16x8 pa  = *(const bf16x8*)&Ps[wv * 32 + l31][ks * 16 + half * 8];
            bf16x8 vf0 = *(const bf16x8*)&Vt[l31][ks * 16 + half * 8];
            bf16x8 vf1 = *(const bf16x8*)&Vt[32 + l31][ks * 16 + half * 8];
            O0 = __builtin_amdgcn_mfma_f32_32x32x16_bf16(pa, vf0, O0, 0, 0, 0);
            O1 = __builtin_amdgcn_mfma_f32_32x32x16_bf16(pa, vf1, O1, 0, 0, 0);
            Lc = __builtin_amdgcn_mfma_f32_32x32x16_bf16(pa, ones, Lc, 0, 0, 0);
        }
        __builtin_amdgcn_s_setprio(0);
    }
    // deterministic per-split partial store (bf16)
    unsigned short* Ob =
        Op + (((size_t)s * BB + b) * TT + ti * 64 + wv * 32) * HH;
    #pragma unroll
    for (int r = 0; r < 16; ++r) {
        int pat = (r & 3) + 8 * (r >> 2) + 4 * half;
        Ob[(size_t)pat * HH + l31]      = f2bf(O0[r]);
        Ob[(size_t)pat * HH + 32 + l31] = f2bf(O1[r]);
    }
    if (l31 == 0) {
        #pragma unroll
        for (int r = 0; r < 16; ++r) {
            int pat = (r & 3) + 8 * (r >> 2) + 4 * half;
            Lp[((size_t)s * BB + b) * TT + ti * 64 + wv * 32 + pat] = Lc[r];
        }
    }
}

// ---------------------------------------------------------------------------
// Kernel 3: out = (sum_s Op[s]) / (sum_s Lp[s]) — unchanged (round-6).
// ---------------------------------------------------------------------------
__global__ __launch_bounds__(256) void norm_out(
        const unsigned short* __restrict__ Op, const float* __restrict__ Lp,
        float* __restrict__ out) {
    int idx = blockIdx.x * 256 + threadIdx.x;     // 65536 total
    int g = idx >> 2;                             // global row b*T + t, <16384
    int hseg = (idx & 3) * 16;
    int ti = (g & (TT - 1)) >> 6;
    int ns = min(ti + 1, NSPLIT);
    float a[16];
    #pragma unroll
    for (int j = 0; j < 16; ++j) a[j] = 0.f;
    float Ls = 0.f;
    for (int s = 0; s < ns; ++s) {
        const unsigned short* base =
            Op + ((size_t)s * BB * TT + g) * HH + hseg;
        us8 u0 = *(const us8*)base;
        us8 u1 = *(const us8*)(base + 8);
        #pragma unroll
        for (int j = 0; j < 8; ++j) { a[j] += bf2f(u0[j]); a[8 + j] += bf2f(u1[j]); }
        Ls += Lp[(size_t)s * BB * TT + g];
    }
    float inv = 1.0f / Ls;
    float* ob = out + (size_t)g * HH + hseg;
    #pragma unroll
    for (int q = 0; q < 4; ++q) {
        float4 v = make_float4(a[q*4] * inv, a[q*4+1] * inv,
                               a[q*4+2] * inv, a[q*4+3] * inv);
        ((float4*)ob)[q] = v;
    }
}

// ---------------------------------------------------------------------------
extern "C" void kernel_launch(void* const* d_in, const int* in_sizes, int n_in,
                              void* d_out, int out_size, void* d_ws, size_t ws_size,
                              hipStream_t stream) {
    (void)in_sizes; (void)n_in; (void)out_size; (void)ws_size;
    const float* x  = (const float*)d_in[0];
    const float* Wq = (const float*)d_in[1];
    const float* Wk = (const float*)d_in[2];
    const float* Wv = (const float*)d_in[3];
    float* out = (float*)d_out;

    char* ws = (char*)d_ws;
    unsigned short* Wt  = (unsigned short*)ws;                          // 384 KB
    unsigned short* qws = (unsigned short*)(ws + (1u << 19));           // 2 MB
    unsigned short* kws = (unsigned short*)(ws + (1u << 19) + (1u << 21));
    unsigned short* vws = (unsigned short*)(ws + (1u << 19) + (2u << 21));
    unsigned short* Op  = (unsigned short*)(ws + (1u << 19) + (3u << 21)); // 8 MB bf16 (4 splits)
    float*          Lp  = (float*)(ws + (1u << 19) + (3u << 21) + (1u << 24)); // 256 KB

    prep_weights<<<48, 256, 0, stream>>>(Wq, Wk, Wv, Wt);
    proj_qkv<<<256, 512, 0, stream>>>(x, Wt, qws, kws, vws);
    attn<<<dim3(32, NSPLIT, 8), 128, 0, stream>>>(qws, kws, vws, Op, Lp);
    norm_out<<<256, 256, 0, stream>>>(Op, Lp, out);
}

// Round 12
// 132.313 us; speedup vs baseline: 1.0811x; 1.0149x over previous
//
#include <hip/hip_runtime.h>
#include <hip/hip_bf16.h>

#define BB 8
#define TT 2048
#define CC 1024
#define HH 64
#define NSPLIT 8

typedef __attribute__((ext_vector_type(8)))  short bf16x8;
typedef __attribute__((ext_vector_type(4)))  float f32x4;
typedef __attribute__((ext_vector_type(16))) float f32x16;
typedef __attribute__((ext_vector_type(8)))  unsigned short us8;
typedef __attribute__((ext_vector_type(4)))  unsigned short us4;
typedef unsigned int u32;

static __device__ __forceinline__ unsigned short f2bf(float f) {
    union { float f; unsigned int u; } v; v.f = f;
    unsigned int u = v.u;
    return (unsigned short)((u + 0x7FFFu + ((u >> 16) & 1u)) >> 16);  // RNE
}
static __device__ __forceinline__ float bf2f(unsigned short s) {
    union { u32 u; float f; } v; v.u = ((u32)s) << 16; return v.f;
}

// ---------------------------------------------------------------------------
// Kernel 0: W [C][H] fp32 -> Wt [3][H][C] bf16 (transposed), fold log2(e)/8
// into Wq so QK^T scores come out in the log2 domain. (unchanged)
// ---------------------------------------------------------------------------
__global__ __launch_bounds__(256) void prep_weights(
        const float* __restrict__ Wq, const float* __restrict__ Wk,
        const float* __restrict__ Wv, unsigned short* __restrict__ Wt) {
    __shared__ float tile[64][65];
    int w  = blockIdx.x >> 4;       // 0..2
    int c0 = (blockIdx.x & 15) * 64;
    const float* W = (w == 0) ? Wq : (w == 1) ? Wk : Wv;
    int li = threadIdx.x;
    {
        int c = li >> 2, h4 = (li & 3) * 16;
        const float* src = W + (size_t)(c0 + c) * HH + h4;
        #pragma unroll
        for (int i = 0; i < 4; ++i) {
            float4 v4 = *(const float4*)(src + i * 4);
            tile[c][h4 + i*4 + 0] = v4.x; tile[c][h4 + i*4 + 1] = v4.y;
            tile[c][h4 + i*4 + 2] = v4.z; tile[c][h4 + i*4 + 3] = v4.w;
        }
    }
    __syncthreads();
    float scale = (w == 0) ? 0.1803368802f : 1.0f;   // log2(e)/sqrt(64)
    int h = li >> 2, cg = (li & 3) * 16;
    unsigned short* dst = Wt + (size_t)w * HH * CC + (size_t)h * CC + c0 + cg;
    #pragma unroll
    for (int i = 0; i < 16; ++i) dst[i] = f2bf(tile[cg + i][h] * scale);
}

// ---------------------------------------------------------------------------
// Kernel 1: fused QKV projection — round-6 PASSED version verbatim (M=64,
// grid 256, vmcnt(2) double-buffer).
// ---------------------------------------------------------------------------
__global__ __launch_bounds__(512, 4) void proj_qkv(
        const float* __restrict__ x, const unsigned short* __restrict__ Wt,
        unsigned short* __restrict__ qws, unsigned short* __restrict__ kws,
        unsigned short* __restrict__ vws) {
    __shared__ unsigned short Xs[2][64 * 64];    // 8 KB each
    __shared__ unsigned short Ws[2][192 * 64];   // 24 KB each
    int tid = threadIdx.x;
    int wv = tid >> 6, lane = tid & 63;
    int quad = (lane >> 4) & 3, lq = lane & 15;
    int mg = wv >> 2, ng = wv & 3;
    int r0 = blockIdx.x * 64;

    int xr = tid >> 3, xg = tid & 7;
    const float* xsrc = x + (size_t)(r0 + xr) * CC + xg * 8;
    int xdst = xr * 64 + ((xg ^ (xr & 7)) * 8);
    float4 xa[2], xb[2];                         // 2-deep prefetch sets

    f32x4 acc[2][3];
    #pragma unroll
    for (int mt = 0; mt < 2; ++mt)
        #pragma unroll
        for (int nt = 0; nt < 3; ++nt)
            #pragma unroll
            for (int i = 0; i < 4; ++i) acc[mt][nt][i] = 0.0f;

    auto stageW = [&](int buf, int kc) {
        #pragma unroll
        for (int i = 0; i < 3; ++i) {
            int fp = tid + i * 512;            // 0..1535
            int r = fp >> 3, pb = fp & 7, g = pb ^ (r & 7);
            const u32 __attribute__((address_space(1)))* gsrc =
                (const u32 __attribute__((address_space(1)))*)
                    (Wt + (size_t)r * CC + kc * 64 + g * 8);
            u32 __attribute__((address_space(3)))* ldst =
                (u32 __attribute__((address_space(3)))*)(&Ws[buf][fp * 8]);
            __builtin_amdgcn_global_load_lds(gsrc, ldst, 16, 0, 0);
        }
    };
    auto loadX = [&](int set, int kc) {
        xa[set] = *(const float4*)(xsrc + kc * 64);
        xb[set] = *(const float4*)(xsrc + kc * 64 + 4);
    };
    auto writeX = [&](int set, int buf) {
        unsigned short h[8];
        h[0]=f2bf(xa[set].x); h[1]=f2bf(xa[set].y);
        h[2]=f2bf(xa[set].z); h[3]=f2bf(xa[set].w);
        h[4]=f2bf(xb[set].x); h[5]=f2bf(xb[set].y);
        h[6]=f2bf(xb[set].z); h[7]=f2bf(xb[set].w);
        *(us8*)&Xs[buf][xdst] = *(const us8*)h;
    };

    stageW(0, 0);
    loadX(0, 0); loadX(1, 1);
    writeX(0, 0);

    for (int kc = 0; kc < 16; ++kc) {
        int cur = kc & 1;
        if (kc < 15) asm volatile("s_waitcnt vmcnt(2) lgkmcnt(0)" ::: "memory");
        else         asm volatile("s_waitcnt vmcnt(0) lgkmcnt(0)" ::: "memory");
        __builtin_amdgcn_sched_barrier(0);
        __builtin_amdgcn_s_barrier();        // all waves' buf[cur] now valid
        if (kc < 15) stageW(1 - cur, kc + 1);
        if (kc < 14) loadX(kc & 1, kc + 2);
        #pragma unroll
        for (int ks = 0; ks < 2; ++ks) {
            int g = ks * 4 + quad;
            bf16x8 a[2], b[3];
            #pragma unroll
            for (int mt = 0; mt < 2; ++mt) {
                int arow = mg * 32 + mt * 16 + lq;
                a[mt] = *(const bf16x8*)&Xs[cur][arow * 64 + (g ^ (lq & 7)) * 8];
            }
            #pragma unroll
            for (int nt = 0; nt < 3; ++nt) {
                int brow = ng * 48 + nt * 16 + lq;
                b[nt] = *(const bf16x8*)&Ws[cur][brow * 64 + (g ^ (lq & 7)) * 8];
            }
            #pragma unroll
            for (int mt = 0; mt < 2; ++mt)
                #pragma unroll
                for (int nt = 0; nt < 3; ++nt)
                    acc[mt][nt] = __builtin_amdgcn_mfma_f32_16x16x32_bf16(
                        a[mt], b[nt], acc[mt][nt], 0, 0, 0);
        }
        if (kc < 15) writeX((kc + 1) & 1, 1 - cur);  // X[kc+1]
    }

    // epilogue: direct q|k|v writes (wave-uniform column buckets).
    int bidx = r0 >> 11;                       // batch
    int t0base = r0 & (TT - 1);
    #pragma unroll
    for (int mt = 0; mt < 2; ++mt) {
        #pragma unroll
        for (int nt = 0; nt < 3; ++nt) {
            int gcol = ng * 48 + nt * 16 + lq;
            int rloc = mg * 32 + mt * 16 + quad * 4;      // + i
            if (gcol < 64) {
                #pragma unroll
                for (int i = 0; i < 4; ++i)
                    qws[(size_t)(r0 + rloc + i) * HH + gcol] =
                        f2bf(acc[mt][nt][i]);
            } else if (gcol < 128) {
                #pragma unroll
                for (int i = 0; i < 4; ++i)
                    kws[(size_t)(r0 + rloc + i) * HH + (gcol - 64)] =
                        f2bf(acc[mt][nt][i]);
            } else {
                unsigned short o[4];
                #pragma unroll
                for (int i = 0; i < 4; ++i) o[i] = f2bf(acc[mt][nt][i]);
                *(us4*)(vws + ((size_t)bidx * HH + (gcol - 128)) * TT
                            + t0base + rloc) = *(const us4*)o;
            }
        }
    }
}

// ---------------------------------------------------------------------------
// Kernel 2: causal attention — q-tile 128, 4 waves/block (round-10 design,
// resubmitted after two infra failures). One K/V staging + barrier pair
// feeds 4 waves; grid-wide chunk-iters halve (4224->2176); LDS 36.9KB ->
// 3 blocks/CU x 4 waves = 12 waves/CU. NSPLIT=8: max 4 iters/block.
// Fully-future chunks skipped via wave-uniform branch (barriers outside).
// ---------------------------------------------------------------------------
__global__ __launch_bounds__(256, 3) void attn(
        const unsigned short* __restrict__ qws,
        const unsigned short* __restrict__ kws,
        const unsigned short* __restrict__ vws,
        unsigned short* __restrict__ Op, float* __restrict__ Lp) {
    __shared__ unsigned short Kt[64][72];    // [key][h]      9.2 KB
    __shared__ unsigned short Vt[64][72];    // [h][key]      9.2 KB
    __shared__ unsigned short Ps[128][72];   // [q][key]     18.4 KB, wave-private rows
    int ti = blockIdx.x;            // 128-row q tile, 0..15
    int s  = blockIdx.y;            // kv split 0..NSPLIT-1
    int b  = blockIdx.z;
    int last = 2 * ti + 1;          // last 64-key chunk index for this tile
    if (s > last) return;
    int tid = threadIdx.x, wv = tid >> 6, lane = tid & 63;
    int half = lane >> 5, l31 = lane & 31;
    int rmin = ti * 128 + wv * 32;  // this wave's first q row (global in tile dim)

    bf16x8 qf[4];
    {
        const unsigned short* qp =
            qws + ((size_t)b * TT + rmin + l31) * HH + half * 8;
        #pragma unroll
        for (int ks = 0; ks < 4; ++ks) qf[ks] = *(const bf16x8*)(qp + ks * 16);
    }
    f32x16 O0, O1, Lc;
    #pragma unroll
    for (int i = 0; i < 16; ++i) { O0[i] = 0.f; O1[i] = 0.f; Lc[i] = 0.f; }
    bf16x8 ones;
    #pragma unroll
    for (int i = 0; i < 8; ++i) ones[i] = (short)0x3F80;

    // staging: 256 threads x 2 rounds x us8 for each of K (64 keys x 64 h)
    // and V (64 h x 64 keys, pre-transposed in vws)
    int sr = tid >> 3, sg = tid & 7;          // sr 0..31
    const unsigned short* ksrc0 = kws + ((size_t)b * TT + sr) * HH + sg * 8;
    const unsigned short* vsrc0 = vws + ((size_t)b * HH + sr) * TT + sg * 8;

    us8 rk[2], rv[2];                          // T14 prefetch registers
    auto loadKV = [&](int jc) {
        #pragma unroll
        for (int i = 0; i < 2; ++i)
            rk[i] = *(const us8*)(ksrc0 + (size_t)(jc * 64 + i * 32) * HH);
        #pragma unroll
        for (int i = 0; i < 2; ++i)
            rv[i] = *(const us8*)(vsrc0 + (size_t)(i * 32) * TT + jc * 64);
    };
    auto writeKV = [&]() {
        #pragma unroll
        for (int i = 0; i < 2; ++i) *(us8*)&Kt[sr + i * 32][sg * 8] = rk[i];
        #pragma unroll
        for (int i = 0; i < 2; ++i) *(us8*)&Vt[sr + i * 32][sg * 8] = rv[i];
    };

    loadKV(s);                                 // prologue prefetch
    for (int jc = s; jc <= last; jc += NSPLIT) {
        __syncthreads();   // prior iter's K/V reads done before restage
        writeKV();
        if (jc + NSPLIT <= last) loadKV(jc + NSPLIT);   // hide under compute
        __syncthreads();
        // wave-uniform skip: chunk entirely in this wave's future -> all-masked
        if (jc * 64 <= rmin + 31) {
            f32x16 S0, S1;
            #pragma unroll
            for (int i = 0; i < 16; ++i) { S0[i] = 0.f; S1[i] = 0.f; }
            __builtin_amdgcn_s_setprio(1);
            #pragma unroll
            for (int ks = 0; ks < 4; ++ks) {
                bf16x8 kf0 = *(const bf16x8*)&Kt[l31][ks * 16 + half * 8];
                bf16x8 kf1 = *(const bf16x8*)&Kt[32 + l31][ks * 16 + half * 8];
                S0 = __builtin_amdgcn_mfma_f32_32x32x16_bf16(qf[ks], kf0, S0, 0, 0, 0);
                S1 = __builtin_amdgcn_mfma_f32_32x32x16_bf16(qf[ks], kf1, S1, 0, 0, 0);
            }
            __builtin_amdgcn_s_setprio(0);
            bool diag = (jc * 64 + 63 > rmin);   // chunk can touch the diagonal
            #pragma unroll
            for (int r = 0; r < 16; ++r) {
                int pat = (r & 3) + 8 * (r >> 2) + 4 * half;  // local q row in wave
                float p0 = __builtin_amdgcn_exp2f(S0[r]);
                float p1 = __builtin_amdgcn_exp2f(S1[r]);
                if (diag) {
                    int row = rmin + pat;          // global q row
                    if (jc * 64 + l31 > row)      p0 = 0.0f;
                    if (jc * 64 + 32 + l31 > row) p1 = 0.0f;
                }
                Ps[wv * 32 + pat][l31]      = f2bf(p0);
                Ps[wv * 32 + pat][32 + l31] = f2bf(p1);
            }
            // no __syncthreads: each wave reads only its own 32 Ps rows
            __builtin_amdgcn_s_setprio(1);
            #pragma unroll
            for (int ks = 0; ks < 4; ++ks) {
                bf16x8 pa  = *(const bf16x8*)&Ps[wv * 32 + l31][ks * 16 + half * 8];
                bf16x8 vf0 = *(const bf16x8*)&Vt[l31][ks * 16 + half * 8];
                bf16x8 vf1 = *(const bf16x8*)&Vt[32 + l31][ks * 16 + half * 8];
                O0 = __builtin_amdgcn_mfma_f32_32x32x16_bf16(pa, vf0, O0, 0, 0, 0);
                O1 = __builtin_amdgcn_mfma_f32_32x32x16_bf16(pa, vf1, O1, 0, 0, 0);
                Lc = __builtin_amdgcn_mfma_f32_32x32x16_bf16(pa, ones, Lc, 0, 0, 0);
            }
            __builtin_amdgcn_s_setprio(0);
        }
    }
    // deterministic per-split partial store (bf16)
    unsigned short* Ob =
        Op + (((size_t)s * BB + b) * TT + rmin) * HH;
    #pragma unroll
    for (int r = 0; r < 16; ++r) {
        int pat = (r & 3) + 8 * (r >> 2) + 4 * half;
        Ob[(size_t)pat * HH + l31]      = f2bf(O0[r]);
        Ob[(size_t)pat * HH + 32 + l31] = f2bf(O1[r]);
    }
    if (l31 == 0) {
        #pragma unroll
        for (int r = 0; r < 16; ++r) {
            int pat = (r & 3) + 8 * (r >> 2) + 4 * half;
            Lp[((size_t)s * BB + b) * TT + rmin + pat] = Lc[r];
        }
    }
}

// ---------------------------------------------------------------------------
// Kernel 3: out = (sum_s Op[s]) / (sum_s Lp[s]) — ns for 128-row tiles +
// NSPLIT=8 (split s active iff s <= 2*ti+1 -> ns = min(2*ti+2, 8)).
// ---------------------------------------------------------------------------
__global__ __launch_bounds__(256) void norm_out(
        const unsigned short* __restrict__ Op, const float* __restrict__ Lp,
        float* __restrict__ out) {
    int idx = blockIdx.x * 256 + threadIdx.x;     // 65536 total
    int g = idx >> 2;                             // global row b*T + t, <16384
    int hseg = (idx & 3) * 16;
    int ti = (g & (TT - 1)) >> 7;                 // 128-row tile index
    int ns = min(2 * ti + 2, NSPLIT);
    float a[16];
    #pragma unroll
    for (int j = 0; j < 16; ++j) a[j] = 0.f;
    float Ls = 0.f;
    for (int s = 0; s < ns; ++s) {
        const unsigned short* base =
            Op + ((size_t)s * BB * TT + g) * HH + hseg;
        us8 u0 = *(const us8*)base;
        us8 u1 = *(const us8*)(base + 8);
        #pragma unroll
        for (int j = 0; j < 8; ++j) { a[j] += bf2f(u0[j]); a[8 + j] += bf2f(u1[j]); }
        Ls += Lp[(size_t)s * BB * TT + g];
    }
    float inv = 1.0f / Ls;
    float* ob = out + (size_t)g * HH + hseg;
    #pragma unroll
    for (int q = 0; q < 4; ++q) {
        float4 v = make_float4(a[q*4] * inv, a[q*4+1] * inv,
                               a[q*4+2] * inv, a[q*4+3] * inv);
        ((float4*)ob)[q] = v;
    }
}

// ---------------------------------------------------------------------------
extern "C" void kernel_launch(void* const* d_in, const int* in_sizes, int n_in,
                              void* d_out, int out_size, void* d_ws, size_t ws_size,
                              hipStream_t stream) {
    (void)in_sizes; (void)n_in; (void)out_size; (void)ws_size;
    const float* x  = (const float*)d_in[0];
    const float* Wq = (const float*)d_in[1];
    const float* Wk = (const float*)d_in[2];
    const float* Wv = (const float*)d_in[3];
    float* out = (float*)d_out;

    char* ws = (char*)d_ws;
    unsigned short* Wt  = (unsigned short*)ws;                          // 384 KB
    unsigned short* qws = (unsigned short*)(ws + (1u << 19));           // 2 MB
    unsigned short* kws = (unsigned short*)(ws + (1u << 19) + (1u << 21));
    unsigned short* vws = (unsigned short*)(ws + (1u << 19) + (2u << 21));
    unsigned short* Op  = (unsigned short*)(ws + (1u << 19) + (3u << 21)); // 16 MB bf16 (8 splits)
    float*          Lp  = (float*)(ws + (1u << 19) + (3u << 21) + (1u << 24)); // 512 KB

    prep_weights<<<48, 256, 0, stream>>>(Wq, Wk, Wv, Wt);
    proj_qkv<<<256, 512, 0, stream>>>(x, Wt, qws, kws, vws);
    attn<<<dim3(16, NSPLIT, 8), 256, 0, stream>>>(qws, kws, vws, Op, Lp);
    norm_out<<<256, 256, 0, stream>>>(Op, Lp, out);
}

// Round 13
// 128.710 us; speedup vs baseline: 1.1114x; 1.0280x over previous
//
#include <hip/hip_runtime.h>
#include <hip/hip_bf16.h>

#define BB 8
#define TT 2048
#define CC 1024
#define HH 64
#define NSPLIT 4

typedef __attribute__((ext_vector_type(8)))  short bf16x8;
typedef __attribute__((ext_vector_type(4)))  float f32x4;
typedef __attribute__((ext_vector_type(16))) float f32x16;
typedef __attribute__((ext_vector_type(8)))  unsigned short us8;
typedef __attribute__((ext_vector_type(4)))  unsigned short us4;
typedef unsigned int u32;

static __device__ __forceinline__ unsigned short f2bf(float f) {
    union { float f; unsigned int u; } v; v.f = f;
    unsigned int u = v.u;
    return (unsigned short)((u + 0x7FFFu + ((u >> 16) & 1u)) >> 16);  // RNE
}
static __device__ __forceinline__ float bf2f(unsigned short s) {
    union { u32 u; float f; } v; v.u = ((u32)s) << 16; return v.f;
}

// ---------------------------------------------------------------------------
// Kernel 0: W [C][H] fp32 -> Wt [3][H][C] bf16 (transposed), fold log2(e)/8
// into Wq so QK^T scores come out in the log2 domain. (unchanged)
// ---------------------------------------------------------------------------
__global__ __launch_bounds__(256) void prep_weights(
        const float* __restrict__ Wq, const float* __restrict__ Wk,
        const float* __restrict__ Wv, unsigned short* __restrict__ Wt) {
    __shared__ float tile[64][65];
    int w  = blockIdx.x >> 4;       // 0..2
    int c0 = (blockIdx.x & 15) * 64;
    const float* W = (w == 0) ? Wq : (w == 1) ? Wk : Wv;
    int li = threadIdx.x;
    {
        int c = li >> 2, h4 = (li & 3) * 16;
        const float* src = W + (size_t)(c0 + c) * HH + h4;
        #pragma unroll
        for (int i = 0; i < 4; ++i) {
            float4 v4 = *(const float4*)(src + i * 4);
            tile[c][h4 + i*4 + 0] = v4.x; tile[c][h4 + i*4 + 1] = v4.y;
            tile[c][h4 + i*4 + 2] = v4.z; tile[c][h4 + i*4 + 3] = v4.w;
        }
    }
    __syncthreads();
    float scale = (w == 0) ? 0.1803368802f : 1.0f;   // log2(e)/sqrt(64)
    int h = li >> 2, cg = (li & 3) * 16;
    unsigned short* dst = Wt + (size_t)w * HH * CC + (size_t)h * CC + c0 + cg;
    #pragma unroll
    for (int i = 0; i < 16; ++i) dst[i] = f2bf(tile[cg + i][h] * scale);
}

// ---------------------------------------------------------------------------
// Kernel 1: fused QKV projection — round-6 PASSED version verbatim (M=64,
// grid 256, vmcnt(2) double-buffer).
// ---------------------------------------------------------------------------
__global__ __launch_bounds__(512, 4) void proj_qkv(
        const float* __restrict__ x, const unsigned short* __restrict__ Wt,
        unsigned short* __restrict__ qws, unsigned short* __restrict__ kws,
        unsigned short* __restrict__ vws) {
    __shared__ unsigned short Xs[2][64 * 64];    // 8 KB each
    __shared__ unsigned short Ws[2][192 * 64];   // 24 KB each
    int tid = threadIdx.x;
    int wv = tid >> 6, lane = tid & 63;
    int quad = (lane >> 4) & 3, lq = lane & 15;
    int mg = wv >> 2, ng = wv & 3;
    int r0 = blockIdx.x * 64;

    int xr = tid >> 3, xg = tid & 7;
    const float* xsrc = x + (size_t)(r0 + xr) * CC + xg * 8;
    int xdst = xr * 64 + ((xg ^ (xr & 7)) * 8);
    float4 xa[2], xb[2];                         // 2-deep prefetch sets

    f32x4 acc[2][3];
    #pragma unroll
    for (int mt = 0; mt < 2; ++mt)
        #pragma unroll
        for (int nt = 0; nt < 3; ++nt)
            #pragma unroll
            for (int i = 0; i < 4; ++i) acc[mt][nt][i] = 0.0f;

    auto stageW = [&](int buf, int kc) {
        #pragma unroll
        for (int i = 0; i < 3; ++i) {
            int fp = tid + i * 512;            // 0..1535
            int r = fp >> 3, pb = fp & 7, g = pb ^ (r & 7);
            const u32 __attribute__((address_space(1)))* gsrc =
                (const u32 __attribute__((address_space(1)))*)
                    (Wt + (size_t)r * CC + kc * 64 + g * 8);
            u32 __attribute__((address_space(3)))* ldst =
                (u32 __attribute__((address_space(3)))*)(&Ws[buf][fp * 8]);
            __builtin_amdgcn_global_load_lds(gsrc, ldst, 16, 0, 0);
        }
    };
    auto loadX = [&](int set, int kc) {
        xa[set] = *(const float4*)(xsrc + kc * 64);
        xb[set] = *(const float4*)(xsrc + kc * 64 + 4);
    };
    auto writeX = [&](int set, int buf) {
        unsigned short h[8];
        h[0]=f2bf(xa[set].x); h[1]=f2bf(xa[set].y);
        h[2]=f2bf(xa[set].z); h[3]=f2bf(xa[set].w);
        h[4]=f2bf(xb[set].x); h[5]=f2bf(xb[set].y);
        h[6]=f2bf(xb[set].z); h[7]=f2bf(xb[set].w);
        *(us8*)&Xs[buf][xdst] = *(const us8*)h;
    };

    stageW(0, 0);
    loadX(0, 0); loadX(1, 1);
    writeX(0, 0);

    for (int kc = 0; kc < 16; ++kc) {
        int cur = kc & 1;
        if (kc < 15) asm volatile("s_waitcnt vmcnt(2) lgkmcnt(0)" ::: "memory");
        else         asm volatile("s_waitcnt vmcnt(0) lgkmcnt(0)" ::: "memory");
        __builtin_amdgcn_sched_barrier(0);
        __builtin_amdgcn_s_barrier();        // all waves' buf[cur] now valid
        if (kc < 15) stageW(1 - cur, kc + 1);
        if (kc < 14) loadX(kc & 1, kc + 2);
        #pragma unroll
        for (int ks = 0; ks < 2; ++ks) {
            int g = ks * 4 + quad;
            bf16x8 a[2], b[3];
            #pragma unroll
            for (int mt = 0; mt < 2; ++mt) {
                int arow = mg * 32 + mt * 16 + lq;
                a[mt] = *(const bf16x8*)&Xs[cur][arow * 64 + (g ^ (lq & 7)) * 8];
            }
            #pragma unroll
            for (int nt = 0; nt < 3; ++nt) {
                int brow = ng * 48 + nt * 16 + lq;
                b[nt] = *(const bf16x8*)&Ws[cur][brow * 64 + (g ^ (lq & 7)) * 8];
            }
            #pragma unroll
            for (int mt = 0; mt < 2; ++mt)
                #pragma unroll
                for (int nt = 0; nt < 3; ++nt)
                    acc[mt][nt] = __builtin_amdgcn_mfma_f32_16x16x32_bf16(
                        a[mt], b[nt], acc[mt][nt], 0, 0, 0);
        }
        if (kc < 15) writeX((kc + 1) & 1, 1 - cur);  // X[kc+1]
    }

    // epilogue: direct q|k|v writes (wave-uniform column buckets).
    int bidx = r0 >> 11;                       // batch
    int t0base = r0 & (TT - 1);
    #pragma unroll
    for (int mt = 0; mt < 2; ++mt) {
        #pragma unroll
        for (int nt = 0; nt < 3; ++nt) {
            int gcol = ng * 48 + nt * 16 + lq;
            int rloc = mg * 32 + mt * 16 + quad * 4;      // + i
            if (gcol < 64) {
                #pragma unroll
                for (int i = 0; i < 4; ++i)
                    qws[(size_t)(r0 + rloc + i) * HH + gcol] =
                        f2bf(acc[mt][nt][i]);
            } else if (gcol < 128) {
                #pragma unroll
                for (int i = 0; i < 4; ++i)
                    kws[(size_t)(r0 + rloc + i) * HH + (gcol - 64)] =
                        f2bf(acc[mt][nt][i]);
            } else {
                unsigned short o[4];
                #pragma unroll
                for (int i = 0; i < 4; ++i) o[i] = f2bf(acc[mt][nt][i]);
                *(us4*)(vws + ((size_t)bidx * HH + (gcol - 128)) * TT
                            + t0base + rloc) = *(const us4*)o;
            }
        }
    }
}

// ---------------------------------------------------------------------------
// Kernel 2: causal attention — ROUND-13: R12's 128-row/4-wave structure
// (halved staging+barrier cost per unit work) + R6's NSPLIT=4 (halves Op
// partial traffic vs R12's NSPLIT=8: avg active splits 7.25 -> 3.875,
// ~14MB HBM saved). Grid (16,4,8)=512 blocks, max 8 iters/block, all
// co-resident (2/CU at 36.9KB LDS). Only grid-y and the split stride change.
// ---------------------------------------------------------------------------
__global__ __launch_bounds__(256, 3) void attn(
        const unsigned short* __restrict__ qws,
        const unsigned short* __restrict__ kws,
        const unsigned short* __restrict__ vws,
        unsigned short* __restrict__ Op, float* __restrict__ Lp) {
    __shared__ unsigned short Kt[64][72];    // [key][h]      9.2 KB
    __shared__ unsigned short Vt[64][72];    // [h][key]      9.2 KB
    __shared__ unsigned short Ps[128][72];   // [q][key]     18.4 KB, wave-private rows
    int ti = blockIdx.x;            // 128-row q tile, 0..15
    int s  = blockIdx.y;            // kv split 0..NSPLIT-1
    int b  = blockIdx.z;
    int last = 2 * ti + 1;          // last 64-key chunk index for this tile
    if (s > last) return;
    int tid = threadIdx.x, wv = tid >> 6, lane = tid & 63;
    int half = lane >> 5, l31 = lane & 31;
    int rmin = ti * 128 + wv * 32;  // this wave's first q row (global in tile dim)

    bf16x8 qf[4];
    {
        const unsigned short* qp =
            qws + ((size_t)b * TT + rmin + l31) * HH + half * 8;
        #pragma unroll
        for (int ks = 0; ks < 4; ++ks) qf[ks] = *(const bf16x8*)(qp + ks * 16);
    }
    f32x16 O0, O1, Lc;
    #pragma unroll
    for (int i = 0; i < 16; ++i) { O0[i] = 0.f; O1[i] = 0.f; Lc[i] = 0.f; }
    bf16x8 ones;
    #pragma unroll
    for (int i = 0; i < 8; ++i) ones[i] = (short)0x3F80;

    // staging: 256 threads x 2 rounds x us8 for each of K (64 keys x 64 h)
    // and V (64 h x 64 keys, pre-transposed in vws)
    int sr = tid >> 3, sg = tid & 7;          // sr 0..31
    const unsigned short* ksrc0 = kws + ((size_t)b * TT + sr) * HH + sg * 8;
    const unsigned short* vsrc0 = vws + ((size_t)b * HH + sr) * TT + sg * 8;

    us8 rk[2], rv[2];                          // T14 prefetch registers
    auto loadKV = [&](int jc) {
        #pragma unroll
        for (int i = 0; i < 2; ++i)
            rk[i] = *(const us8*)(ksrc0 + (size_t)(jc * 64 + i * 32) * HH);
        #pragma unroll
        for (int i = 0; i < 2; ++i)
            rv[i] = *(const us8*)(vsrc0 + (size_t)(i * 32) * TT + jc * 64);
    };
    auto writeKV = [&]() {
        #pragma unroll
        for (int i = 0; i < 2; ++i) *(us8*)&Kt[sr + i * 32][sg * 8] = rk[i];
        #pragma unroll
        for (int i = 0; i < 2; ++i) *(us8*)&Vt[sr + i * 32][sg * 8] = rv[i];
    };

    loadKV(s);                                 // prologue prefetch
    for (int jc = s; jc <= last; jc += NSPLIT) {
        __syncthreads();   // prior iter's K/V reads done before restage
        writeKV();
        if (jc + NSPLIT <= last) loadKV(jc + NSPLIT);   // hide under compute
        __syncthreads();
        // wave-uniform skip: chunk entirely in this wave's future -> all-masked
        if (jc * 64 <= rmin + 31) {
            f32x16 S0, S1;
            #pragma unroll
            for (int i = 0; i < 16; ++i) { S0[i] = 0.f; S1[i] = 0.f; }
            __builtin_amdgcn_s_setprio(1);
            #pragma unroll
            for (int ks = 0; ks < 4; ++ks) {
                bf16x8 kf0 = *(const bf16x8*)&Kt[l31][ks * 16 + half * 8];
                bf16x8 kf1 = *(const bf16x8*)&Kt[32 + l31][ks * 16 + half * 8];
                S0 = __builtin_amdgcn_mfma_f32_32x32x16_bf16(qf[ks], kf0, S0, 0, 0, 0);
                S1 = __builtin_amdgcn_mfma_f32_32x32x16_bf16(qf[ks], kf1, S1, 0, 0, 0);
            }
            __builtin_amdgcn_s_setprio(0);
            bool diag = (jc * 64 + 63 > rmin);   // chunk can touch the diagonal
            #pragma unroll
            for (int r = 0; r < 16; ++r) {
                int pat = (r & 3) + 8 * (r >> 2) + 4 * half;  // local q row in wave
                float p0 = __builtin_amdgcn_exp2f(S0[r]);
                float p1 = __builtin_amdgcn_exp2f(S1[r]);
                if (diag) {
                    int row = rmin + pat;          // global q row
                    if (jc * 64 + l31 > row)      p0 = 0.0f;
                    if (jc * 64 + 32 + l31 > row) p1 = 0.0f;
                }
                Ps[wv * 32 + pat][l31]      = f2bf(p0);
                Ps[wv * 32 + pat][32 + l31] = f2bf(p1);
            }
            // no __syncthreads: each wave reads only its own 32 Ps rows
            __builtin_amdgcn_s_setprio(1);
            #pragma unroll
            for (int ks = 0; ks < 4; ++ks) {
                bf16x8 pa  = *(const bf16x8*)&Ps[wv * 32 + l31][ks * 16 + half * 8];
                bf16x8 vf0 = *(const bf16x8*)&Vt[l31][ks * 16 + half * 8];
                bf16x8 vf1 = *(const bf16x8*)&Vt[32 + l31][ks * 16 + half * 8];
                O0 = __builtin_amdgcn_mfma_f32_32x32x16_bf16(pa, vf0, O0, 0, 0, 0);
                O1 = __builtin_amdgcn_mfma_f32_32x32x16_bf16(pa, vf1, O1, 0, 0, 0);
                Lc = __builtin_amdgcn_mfma_f32_32x32x16_bf16(pa, ones, Lc, 0, 0, 0);
            }
            __builtin_amdgcn_s_setprio(0);
        }
    }
    // deterministic per-split partial store (bf16)
    unsigned short* Ob =
        Op + (((size_t)s * BB + b) * TT + rmin) * HH;
    #pragma unroll
    for (int r = 0; r < 16; ++r) {
        int pat = (r & 3) + 8 * (r >> 2) + 4 * half;
        Ob[(size_t)pat * HH + l31]      = f2bf(O0[r]);
        Ob[(size_t)pat * HH + 32 + l31] = f2bf(O1[r]);
    }
    if (l31 == 0) {
        #pragma unroll
        for (int r = 0; r < 16; ++r) {
            int pat = (r & 3) + 8 * (r >> 2) + 4 * half;
            Lp[((size_t)s * BB + b) * TT + rmin + pat] = Lc[r];
        }
    }
}

// ---------------------------------------------------------------------------
// Kernel 3: out = (sum_s Op[s]) / (sum_s Lp[s]) — ns for 128-row tiles +
// NSPLIT=4 (split s active iff s <= 2*ti+1 -> ns = min(2*ti+2, 4)).
// ---------------------------------------------------------------------------
__global__ __launch_bounds__(256) void norm_out(
        const unsigned short* __restrict__ Op, const float* __restrict__ Lp,
        float* __restrict__ out) {
    int idx = blockIdx.x * 256 + threadIdx.x;     // 65536 total
    int g = idx >> 2;                             // global row b*T + t, <16384
    int hseg = (idx & 3) * 16;
    int ti = (g & (TT - 1)) >> 7;                 // 128-row tile index
    int ns = min(2 * ti + 2, NSPLIT);
    float a[16];
    #pragma unroll
    for (int j = 0; j < 16; ++j) a[j] = 0.f;
    float Ls = 0.f;
    for (int s = 0; s < ns; ++s) {
        const unsigned short* base =
            Op + ((size_t)s * BB * TT + g) * HH + hseg;
        us8 u0 = *(const us8*)base;
        us8 u1 = *(const us8*)(base + 8);
        #pragma unroll
        for (int j = 0; j < 8; ++j) { a[j] += bf2f(u0[j]); a[8 + j] += bf2f(u1[j]); }
        Ls += Lp[(size_t)s * BB * TT + g];
    }
    float inv = 1.0f / Ls;
    float* ob = out + (size_t)g * HH + hseg;
    #pragma unroll
    for (int q = 0; q < 4; ++q) {
        float4 v = make_float4(a[q*4] * inv, a[q*4+1] * inv,
                               a[q*4+2] * inv, a[q*4+3] * inv);
        ((float4*)ob)[q] = v;
    }
}

// ---------------------------------------------------------------------------
extern "C" void kernel_launch(void* const* d_in, const int* in_sizes, int n_in,
                              void* d_out, int out_size, void* d_ws, size_t ws_size,
                              hipStream_t stream) {
    (void)in_sizes; (void)n_in; (void)out_size; (void)ws_size;
    const float* x  = (const float*)d_in[0];
    const float* Wq = (const float*)d_in[1];
    const float* Wk = (const float*)d_in[2];
    const float* Wv = (const float*)d_in[3];
    float* out = (float*)d_out;

    char* ws = (char*)d_ws;
    unsigned short* Wt  = (unsigned short*)ws;                          // 384 KB
    unsigned short* qws = (unsigned short*)(ws + (1u << 19));           // 2 MB
    unsigned short* kws = (unsigned short*)(ws + (1u << 19) + (1u << 21));
    unsigned short* vws = (unsigned short*)(ws + (1u << 19) + (2u << 21));
    unsigned short* Op  = (unsigned short*)(ws + (1u << 19) + (3u << 21)); // 8 MB bf16 (4 splits)
    float*          Lp  = (float*)(ws + (1u << 19) + (3u << 21) + (1u << 24)); // 256 KB

    prep_weights<<<48, 256, 0, stream>>>(Wq, Wk, Wv, Wt);
    proj_qkv<<<256, 512, 0, stream>>>(x, Wt, qws, kws, vws);
    attn<<<dim3(16, NSPLIT, 8), 256, 0, stream>>>(qws, kws, vws, Op, Lp);
    norm_out<<<256, 256, 0, stream>>>(Op, Lp, out);
}